// Round 6
// baseline (132.228 us; speedup 1.0000x reference)
//
#include <hip/hip_runtime.h>
#include <hip/hip_bf16.h>

typedef __attribute__((ext_vector_type(8))) short short8;
typedef __attribute__((ext_vector_type(8))) __bf16 bf16x8;
typedef __attribute__((ext_vector_type(4))) float f32x4;

#define MFMA(a, b, c) __builtin_amdgcn_mfma_f32_16x16x32_bf16((a), (b), (c), 0, 0, 0)
#define SCALE 0.0625f

static __device__ __forceinline__ void gload16(const void* g, void* l) {
  __builtin_amdgcn_global_load_lds(
      (const __attribute__((address_space(1))) void*)g,
      (__attribute__((address_space(3))) void*)l, 16, 0, 0);
}

static __device__ __forceinline__ unsigned short f2b(float f) {
  union { __hip_bfloat16 h; unsigned short u; } cv;
  cv.h = __float2bfloat16(f);
  return cv.u;
}

// ---- x (f32) -> bf16, 8 elems/thread ---------------------------------------
__global__ __launch_bounds__(256) void convert_x_kern(const float* __restrict__ x,
                                                      unsigned short* __restrict__ xb) {
  long i = ((long)blockIdx.x * 256 + threadIdx.x) * 8;
  float4 a = *reinterpret_cast<const float4*>(x + i);
  float4 b = *reinterpret_cast<const float4*>(x + i + 4);
  short8 o;
  o[0] = (short)f2b(a.x); o[1] = (short)f2b(a.y); o[2] = (short)f2b(a.z); o[3] = (short)f2b(a.w);
  o[4] = (short)f2b(b.x); o[5] = (short)f2b(b.y); o[6] = (short)f2b(b.z); o[7] = (short)f2b(b.w);
  *reinterpret_cast<short8*>(xb + i) = o;
}

// ---- pack biases into one [1536] f32 buffer --------------------------------
__global__ void pack_bias_kern(const float* __restrict__ bq, const float* __restrict__ bk,
                               const float* __restrict__ bv, float* __restrict__ bc) {
  int i = blockIdx.x * 256 + threadIdx.x;
  float v = (i < 256) ? bq[i] : (i < 512) ? bk[i - 256] : bv[i - 512];
  bc[i] = v;
}

// ---- transpose f32 [R][C] -> bf16 [C][R], 64x64 tiles ----------------------
__global__ __launch_bounds__(256) void transpose_w_kern(const float* __restrict__ src,
                                                        unsigned short* __restrict__ dst,
                                                        int ldsrc, int lddst) {
  __shared__ __align__(16) unsigned short tile[64][72];
  int r0 = blockIdx.y * 64, c0 = blockIdx.x * 64;
  int t = threadIdx.x;
  #pragma unroll
  for (int it = 0; it < 4; ++it) {
    int idx = it * 1024 + t * 4;
    int row = idx >> 6, col = idx & 63;
    float4 v = *reinterpret_cast<const float4*>(src + (long)(r0 + row) * ldsrc + c0 + col);
    tile[row][col + 0] = f2b(v.x); tile[row][col + 1] = f2b(v.y);
    tile[row][col + 2] = f2b(v.z); tile[row][col + 3] = f2b(v.w);
  }
  __syncthreads();
  #pragma unroll
  for (int it = 0; it < 4; ++it) {
    int idx = it * 1024 + t * 4;
    int orow = idx >> 6, ocol = idx & 63;
    ushort4 o;
    o.x = tile[ocol + 0][orow]; o.y = tile[ocol + 1][orow];
    o.z = tile[ocol + 2][orow]; o.w = tile[ocol + 3][orow];
    *reinterpret_cast<ushort4*>(dst + (long)(c0 + orow) * lddst + r0 + ocol) = o;
  }
}

// ---- transpose bf16 [R][C] -> [C][R], batched (for V) ----------------------
__global__ __launch_bounds__(256) void transpose_v_kern(const unsigned short* __restrict__ src0,
                                                        unsigned short* __restrict__ dst0,
                                                        int ldsrc, int lddst,
                                                        long sbatch, long dbatch) {
  const unsigned short* src = src0 + (long)blockIdx.z * sbatch;
  unsigned short* dst = dst0 + (long)blockIdx.z * dbatch;
  __shared__ __align__(16) unsigned short tile[64][72];
  int r0 = blockIdx.y * 64, c0 = blockIdx.x * 64;
  int t = threadIdx.x;
  #pragma unroll
  for (int it = 0; it < 2; ++it) {
    int idx = it * 2048 + t * 8;
    int row = idx >> 6, col = idx & 63;
    short8 v = *reinterpret_cast<const short8*>(src + (long)(r0 + row) * ldsrc + c0 + col);
    *reinterpret_cast<short8*>(&tile[row][col]) = v;
  }
  __syncthreads();
  #pragma unroll
  for (int it = 0; it < 2; ++it) {
    int idx = it * 2048 + t * 8;
    int orow = idx >> 6, ocol = idx & 63;
    short8 o;
    #pragma unroll
    for (int i = 0; i < 8; ++i) o[i] = (short)tile[ocol + i][orow];
    *reinterpret_cast<short8*>(dst + (long)(c0 + orow) * lddst + r0 + ocol) = o;
  }
}

// ============================================================================
// Deep-pipelined GEMM, staging-BW-aware: C[M][N] = A[M][K] * B[N][K]^T
// BK=32, BN=256, BM in {128,256}. 512 threads = 8 waves (2M x 4N).
// 4 LDS buffers; stage tile t+3 during tile t (loads aged 2 full tiles at
// their wait). vmcnt(2L) at tile end ensures tile t+1 complete (in-flight
// before wait = t+1,t+2,t+3 = 3L; leave 2L). NT-edge chain: NT-3 -> L,
// NT-2 -> 0. Per-tile NPH=BM/128 phases of 16 MFMA: {ds_reads | stage ->
// s_barrier -> lgkmcnt(0)+sched_barrier -> setprio(1) MFMA setprio(0) ->
// [last phase: vmcnt] -> s_barrier}.
// LDS rows are 64B (BK=32); chunk swizzle: slot = chunk ^ (row&3), applied
// inversely on the global source (rule: both-sides-or-neither). Balanced:
// each bank serves exactly 8 words per wave b128 read (the minimum).
// SWZ grid maps give XCD affinity: 0=QKV (tm panels per XCD, wt L2-resident),
// 1=score / 2=PV (batch b -> XCD pair {2b,2b+1}: per-batch K/V panels stay
// in their own XCD's L2 instead of thrashing across 8).
// ============================================================================
template <int BM, int SWZ, bool BF16OUT, bool BIAS, bool RS, bool EXPSUM>
__global__ __launch_bounds__(512, 2) void gemm_dp(
    const unsigned short* __restrict__ A, const unsigned short* __restrict__ B,
    const float* __restrict__ bias, void* __restrict__ Cout,
    int NT, int lda, int ldb, int ldc,
    long batchA, long batchB, long batchC,
    const float* __restrict__ rowscale,
    float* __restrict__ lpart) {
  constexpr int NPH = BM / 128;           // phases per K-tile
  constexpr int WM = BM / 2;              // wave tile rows
  constexpr int ASH = BM * 32;            // A tile shorts
  constexpr int TSH = ASH + 256 * 32;     // tile shorts
  constexpr int LA = BM / 128;            // A stage rounds/thread
  constexpr int L = LA + 2;               // loads/thread/tile
  __shared__ __align__(128) unsigned short lds[4 * TSH];

  int bid = blockIdx.x;
  int b = 0, tm, tn;
  if constexpr (SWZ == 0) {               // QKV: 192 = 8 xcd * (4 tm * 6 tn)
    int xcd = bid & 7, s = bid >> 3;
    tm = xcd * 4 + s / 6; tn = s % 6;
  } else if constexpr (SWZ == 1) {        // score: 256 = 8 xcd * 32
    int xcd = bid & 7, s = bid >> 3;
    b = xcd >> 1; tm = (xcd & 1) * 4 + (s >> 3); tn = s & 7;
  } else {                                // PV: 256 = 8 xcd * 32
    int xcd = bid & 7, s = bid >> 3;
    b = xcd >> 1; tm = (xcd & 1) * 8 + (s >> 2); tn = s & 3;
  }

  int t = threadIdx.x, w = t >> 6, l = t & 63;
  int wr = w >> 2, wc = w & 3;            // 2 x 4 wave grid
  int g = l >> 4, c = l & 15;

  f32x4 acc[WM / 16][4];
  #pragma unroll
  for (int m = 0; m < WM / 16; ++m)
    #pragma unroll
    for (int n = 0; n < 4; ++n) acc[m][n] = (f32x4){0.f, 0.f, 0.f, 0.f};

  const unsigned short* aptr = A + (long)b * batchA + (long)(tm * BM) * lda;
  const unsigned short* bptr = B + (long)b * batchB + (long)(tn * 256) * ldb;

  int srow = t >> 2;                      // 0..127 row within staging round
  int schunk = (t & 3) ^ (srow & 3);      // inverse-swizzled source chunk

  auto stage = [&](int buf, int kt2, int ph) {
    int k0 = kt2 * 32;
    if (NPH == 1 || ph == 0) {
      #pragma unroll
      for (int r = 0; r < LA; ++r) {
        int row = r * 128 + srow;
        gload16(aptr + (long)row * lda + k0 + schunk * 8,
                lds + buf * TSH + r * 4096 + t * 8);
      }
    }
    if (NPH == 1 || ph == 1) {
      #pragma unroll
      for (int r = 0; r < 2; ++r) {
        int row = r * 128 + srow;
        gload16(bptr + (long)row * ldb + k0 + schunk * 8,
                lds + buf * TSH + ASH + r * 4096 + t * 8);
      }
    }
  };

  // prologue: stage tiles 0,1,2; wait tile 0 (leave 2L newest in flight)
  #pragma unroll
  for (int p = 0; p < NPH; ++p) stage(0, 0, p);
  #pragma unroll
  for (int p = 0; p < NPH; ++p) stage(1, 1, p);
  #pragma unroll
  for (int p = 0; p < NPH; ++p) stage(2, 2, p);
  if constexpr (L == 4) asm volatile("s_waitcnt vmcnt(8)" ::: "memory");
  else                  asm volatile("s_waitcnt vmcnt(6)" ::: "memory");
  __builtin_amdgcn_s_barrier();

  int cxor = (c & 3) << 4;                // row&3 == c&3 for all frag rows
  for (int kt = 0; kt < NT; ++kt) {
    int cur = kt & 3;
    const char* abase = (const char*)lds + (long)cur * TSH * 2;
    const char* bbase = abase + ASH * 2;
    bf16x8 bfr[4];
    #pragma unroll
    for (int ph = 0; ph < NPH; ++ph) {
      bf16x8 af[4];
      #pragma unroll
      for (int m = 0; m < 4; ++m) {
        int row = wr * WM + ph * 64 + m * 16 + c;
        af[m] = *reinterpret_cast<const bf16x8*>(abase + row * 64 + (((g << 4) ^ cxor) & 48));
      }
      if (ph == 0) {
        #pragma unroll
        for (int n = 0; n < 4; ++n) {
          int row = wc * 64 + n * 16 + c;
          bfr[n] = *reinterpret_cast<const bf16x8*>(bbase + row * 64 + (((g << 4) ^ cxor) & 48));
        }
      }
      if (kt + 3 < NT) stage((kt + 3) & 3, kt + 3, ph);
      __builtin_amdgcn_s_barrier();
      asm volatile("s_waitcnt lgkmcnt(0)" ::: "memory");
      __builtin_amdgcn_sched_barrier(0);
      __builtin_amdgcn_s_setprio(1);
      #pragma unroll
      for (int m = 0; m < 4; ++m)
        #pragma unroll
        for (int n = 0; n < 4; ++n)
          acc[ph * 4 + m][n] = MFMA(af[m], bfr[n], acc[ph * 4 + m][n]);
      __builtin_amdgcn_s_setprio(0);
      if (ph == NPH - 1) {                // counted wait: tile kt+1 complete
        if (kt < NT - 3) {
          if constexpr (L == 4) asm volatile("s_waitcnt vmcnt(8)" ::: "memory");
          else                  asm volatile("s_waitcnt vmcnt(6)" ::: "memory");
        } else if (kt == NT - 3) {
          if constexpr (L == 4) asm volatile("s_waitcnt vmcnt(4)" ::: "memory");
          else                  asm volatile("s_waitcnt vmcnt(3)" ::: "memory");
        } else if (kt == NT - 2) {
          asm volatile("s_waitcnt vmcnt(0)" ::: "memory");
        }
      }
      __builtin_amdgcn_s_barrier();
    }
  }

  // ---- epilogue: C/D layout col = lane&15, row = (lane>>4)*4 + j ----
  int r0 = tm * BM + wr * WM + g * 4;
  int c0 = tn * 256 + wc * 64 + c;

  if constexpr (EXPSUM) {
    __shared__ float lred[4][BM];
    #pragma unroll
    for (int m = 0; m < WM / 16; ++m) {
      #pragma unroll
      for (int j = 0; j < 4; ++j) {
        long ob = (long)b * batchC + (long)(r0 + m * 16 + j) * ldc + c0;
        float rs = 0.f;
        #pragma unroll
        for (int n = 0; n < 4; ++n) {
          float pv = __expf(acc[m][n][j] * SCALE);
          ((unsigned short*)Cout)[ob + n * 16] = f2b(pv);
          rs += pv;
        }
        rs += __shfl_xor(rs, 1); rs += __shfl_xor(rs, 2);
        rs += __shfl_xor(rs, 4); rs += __shfl_xor(rs, 8);
        if (c == 0) lred[wc][wr * WM + m * 16 + g * 4 + j] = rs;
      }
    }
    __syncthreads();
    for (int rr = t; rr < BM; rr += 512) {
      float s = lred[0][rr] + lred[1][rr] + lred[2][rr] + lred[3][rr];
      lpart[((long)b * 2048 + tm * BM + rr) * 8 + tn] = s;
    }
  } else {
    #pragma unroll
    for (int m = 0; m < WM / 16; ++m) {
      float lv[4];
      if (RS) {
        #pragma unroll
        for (int j = 0; j < 4; ++j)
          lv[j] = rowscale[(long)b * 2048 + r0 + m * 16 + j];
      }
      #pragma unroll
      for (int n = 0; n < 4; ++n) {
        int col = c0 + n * 16;
        float bv = BIAS ? bias[col] : 0.f;
        long rowb = (long)b * batchC + (long)(r0 + m * 16) * ldc + col;
        #pragma unroll
        for (int j = 0; j < 4; ++j) {
          float v = acc[m][n][j] + bv;
          if (RS) v *= lv[j];
          if (BF16OUT) ((unsigned short*)Cout)[rowb + (long)j * ldc] = f2b(v);
          else         ((float*)Cout)[rowb + (long)j * ldc] = v;
        }
      }
    }
  }
}

// ---- 1/rowsum (8 partials per row) -----------------------------------------
__global__ __launch_bounds__(256) void linv_kern(const float* __restrict__ lpart,
                                                 float* __restrict__ linv) {
  int r = blockIdx.x * 256 + threadIdx.x;  // 8192 rows
  float s = 0.f;
  #pragma unroll
  for (int i = 0; i < 8; ++i) s += lpart[(long)r * 8 + i];
  linv[r] = 1.f / s;
}

extern "C" void kernel_launch(void* const* d_in, const int* in_sizes, int n_in,
                              void* d_out, int out_size, void* d_ws, size_t ws_size,
                              hipStream_t stream) {
  (void)in_sizes; (void)n_in; (void)out_size; (void)ws_size;
  const float* x  = (const float*)d_in[0];
  const float* Wq = (const float*)d_in[1];
  const float* bq = (const float*)d_in[2];
  const float* Wk = (const float*)d_in[3];
  const float* bk = (const float*)d_in[4];
  const float* Wv = (const float*)d_in[5];
  const float* bv = (const float*)d_in[6];
  float* out = (float*)d_out;
  char* ws = (char*)d_ws;

  // ws layout (bytes). lpart/linv overlay xb's region: xb is dead after the
  // QKV GEMM, and score/linv run strictly after it (stream-ordered).
  unsigned short* xb   = (unsigned short*)(ws + 0);          // 16,777,216
  float*          lpart= (float*)         (ws + 0);          //    262,144 (overlay)
  float*          linv = (float*)         (ws + 262144);     //     32,768 (overlay)
  unsigned short* wt   = (unsigned short*)(ws + 16777216);   //  3,145,728  [1536][1024]
  float*          bc   = (float*)         (ws + 19922944);   //      6,144
  unsigned short* qkv  = (unsigned short*)(ws + 19929088);   // 25,165,824  [8192][1536]
  unsigned short* vT   = (unsigned short*)(ws + 45094912);   // 16,777,216  [4][1024][2048]
  unsigned short* attn = (unsigned short*)(ws + 61872128);   // 33,554,432  [4][2048][2048]

  convert_x_kern<<<4096, 256, 0, stream>>>(x, xb);
  pack_bias_kern<<<6, 256, 0, stream>>>(bq, bk, bv, bc);
  transpose_w_kern<<<dim3(4, 16), 256, 0, stream>>>(Wq, wt,              256, 1024);
  transpose_w_kern<<<dim3(4, 16), 256, 0, stream>>>(Wk, wt + 256 * 1024, 256, 1024);
  transpose_w_kern<<<dim3(16, 16), 256, 0, stream>>>(Wv, wt + 512 * 1024, 1024, 1024);

  // qkv[8192][1536] = xb[8192][1024] @ wt[1536][1024]^T + bias
  gemm_dp<256, 0, true, true, false, false><<<dim3(192), 512, 0, stream>>>(
      xb, wt, bc, qkv, 32, 1024, 1024, 1536, 0, 0, 0, nullptr, nullptr);

  // vT[b][do][s] = v[b][s][do]
  transpose_v_kern<<<dim3(16, 32, 4), 256, 0, stream>>>(
      qkv + 512, vT, 1536, 2048, (long)2048 * 1536, (long)1024 * 2048);

  // attn[b][q][k] = exp(q.k/16) (unnormalized) + row partial sums
  gemm_dp<256, 1, true, false, false, true><<<dim3(256), 512, 0, stream>>>(
      qkv, qkv + 256, nullptr, attn, 8, 1536, 1536, 2048,
      (long)2048 * 1536, (long)2048 * 1536, (long)2048 * 2048, nullptr, lpart);
  linv_kern<<<32, 256, 0, stream>>>(lpart, linv);

  // out[b][s][do] = (attn[b][s][:] @ vT[b][do][:]^T) * linv[b][s]
  gemm_dp<128, 2, false, false, true, false><<<dim3(256), 512, 0, stream>>>(
      attn, vT, nullptr, out, 64, 2048, 2048, 1024,
      (long)2048 * 2048, (long)1024 * 2048, (long)2048 * 1024, linv, nullptr);
}

// Round 7
// 123.667 us; speedup vs baseline: 1.0692x; 1.0692x over previous
//
#include <hip/hip_runtime.h>
#include <hip/hip_bf16.h>

typedef __attribute__((ext_vector_type(8))) short short8;
typedef __attribute__((ext_vector_type(8))) __bf16 bf16x8;
typedef __attribute__((ext_vector_type(4))) float f32x4;

#define MFMA(a, b, c) __builtin_amdgcn_mfma_f32_16x16x32_bf16((a), (b), (c), 0, 0, 0)
#define SCALE 0.0625f

static __device__ __forceinline__ void gload16(const void* g, void* l) {
  __builtin_amdgcn_global_load_lds(
      (const __attribute__((address_space(1))) void*)g,
      (__attribute__((address_space(3))) void*)l, 16, 0, 0);
}

static __device__ __forceinline__ unsigned short f2b(float f) {
  union { __hip_bfloat16 h; unsigned short u; } cv;
  cv.h = __float2bfloat16(f);
  return cv.u;
}

// ---- x (f32) -> bf16, 8 elems/thread ---------------------------------------
__global__ __launch_bounds__(256) void convert_x_kern(const float* __restrict__ x,
                                                      unsigned short* __restrict__ xb) {
  long i = ((long)blockIdx.x * 256 + threadIdx.x) * 8;
  float4 a = *reinterpret_cast<const float4*>(x + i);
  float4 b = *reinterpret_cast<const float4*>(x + i + 4);
  short8 o;
  o[0] = (short)f2b(a.x); o[1] = (short)f2b(a.y); o[2] = (short)f2b(a.z); o[3] = (short)f2b(a.w);
  o[4] = (short)f2b(b.x); o[5] = (short)f2b(b.y); o[6] = (short)f2b(b.z); o[7] = (short)f2b(b.w);
  *reinterpret_cast<short8*>(xb + i) = o;
}

// ---- pack biases into one [1536] f32 buffer --------------------------------
__global__ void pack_bias_kern(const float* __restrict__ bq, const float* __restrict__ bk,
                               const float* __restrict__ bv, float* __restrict__ bc) {
  int i = blockIdx.x * 256 + threadIdx.x;
  float v = (i < 256) ? bq[i] : (i < 512) ? bk[i - 256] : bv[i - 512];
  bc[i] = v;
}

// ---- transpose f32 [R][C] -> bf16 [C][R], 64x64 tiles ----------------------
__global__ __launch_bounds__(256) void transpose_w_kern(const float* __restrict__ src,
                                                        unsigned short* __restrict__ dst,
                                                        int ldsrc, int lddst) {
  __shared__ __align__(16) unsigned short tile[64][72];
  int r0 = blockIdx.y * 64, c0 = blockIdx.x * 64;
  int t = threadIdx.x;
  #pragma unroll
  for (int it = 0; it < 4; ++it) {
    int idx = it * 1024 + t * 4;
    int row = idx >> 6, col = idx & 63;
    float4 v = *reinterpret_cast<const float4*>(src + (long)(r0 + row) * ldsrc + c0 + col);
    tile[row][col + 0] = f2b(v.x); tile[row][col + 1] = f2b(v.y);
    tile[row][col + 2] = f2b(v.z); tile[row][col + 3] = f2b(v.w);
  }
  __syncthreads();
  #pragma unroll
  for (int it = 0; it < 4; ++it) {
    int idx = it * 1024 + t * 4;
    int orow = idx >> 6, ocol = idx & 63;
    ushort4 o;
    o.x = tile[ocol + 0][orow]; o.y = tile[ocol + 1][orow];
    o.z = tile[ocol + 2][orow]; o.w = tile[ocol + 3][orow];
    *reinterpret_cast<ushort4*>(dst + (long)(c0 + orow) * lddst + r0 + ocol) = o;
  }
}

// ---- transpose bf16 [R][C] -> [C][R], batched (for V) ----------------------
__global__ __launch_bounds__(256) void transpose_v_kern(const unsigned short* __restrict__ src0,
                                                        unsigned short* __restrict__ dst0,
                                                        int ldsrc, int lddst,
                                                        long sbatch, long dbatch) {
  const unsigned short* src = src0 + (long)blockIdx.z * sbatch;
  unsigned short* dst = dst0 + (long)blockIdx.z * dbatch;
  __shared__ __align__(16) unsigned short tile[64][72];
  int r0 = blockIdx.y * 64, c0 = blockIdx.x * 64;
  int t = threadIdx.x;
  #pragma unroll
  for (int it = 0; it < 2; ++it) {
    int idx = it * 2048 + t * 8;
    int row = idx >> 6, col = idx & 63;
    short8 v = *reinterpret_cast<const short8*>(src + (long)(r0 + row) * ldsrc + c0 + col);
    *reinterpret_cast<short8*>(&tile[row][col]) = v;
  }
  __syncthreads();
  #pragma unroll
  for (int it = 0; it < 2; ++it) {
    int idx = it * 2048 + t * 8;
    int orow = idx >> 6, ocol = idx & 63;
    short8 o;
    #pragma unroll
    for (int i = 0; i < 8; ++i) o[i] = (short)tile[ocol + i][orow];
    *reinterpret_cast<short8*>(dst + (long)(c0 + orow) * lddst + r0 + ocol) = o;
  }
}

// ============================================================================
// Phase-interleaved GEMM v3: C[M][N] = A[M][K] * B[N][K]^T. BK=64, BN=256.
// 512 threads = 8 waves (2M x 4N).
//
// BM=256: wave tile 128x64 (24 ds_read per 64 MFMA -> MFMA-bound). 2-buffer
//   LDS (128KB). 4 phases/K-tile (kh,mh); B-frags register-reused across mh.
//   Stage order for tile t+1 during t: p0:{B0,B1} p1:{B2,B3} p2:{A0,A2}
//   p3:{A1,A3} (A round r = rows 64r..64r+63; mh0 needs rounds {0,2}).
//   Counted waits: tile-end vmcnt(2) retires B*4+A0+A2 (all data needed at
//   t+1 phases 0..1); p0-end vmcnt(2) retires A1,A3 (needed at p1, mh=1).
//   Last tile: p0-end vmcnt(0), no tile-end wait.
// BM=128: wave tile 64x64. 3-buffer LDS (144KB), stage t+2, 2 phases (kh),
//   tile-end vmcnt(6) (r4-proven), NT-2 -> vmcnt(0).
// Phase body: {ds_reads | 2-3 stage loads -> s_barrier -> lgkmcnt(0)+
//   sched_barrier -> setprio(1) 16 MFMA setprio(0) -> [wait] -> s_barrier}.
// Reads of phase p+1 overlap other waves' MFMA bursts of phase p.
// 128B-row XOR swizzle (0 bank conflicts, r4-verified).
// SWZ XCD-affinity maps: 0=QKV, 1=score, 2=PV (batch -> XCD pair).
// ============================================================================
template <int BM, int SWZ, bool BF16OUT, bool BIAS, bool RS, bool EXPSUM>
__global__ __launch_bounds__(512, 2) void gemm_pi(
    const unsigned short* __restrict__ A, const unsigned short* __restrict__ B,
    const float* __restrict__ bias, void* __restrict__ Cout,
    int NT, int lda, int ldb, int ldc,
    long batchA, long batchB, long batchC,
    const float* __restrict__ rowscale,
    float* __restrict__ lpart) {
  constexpr int WM = BM / 2;              // wave rows
  constexpr int MH = WM / 64;             // A row-halves per wave (2 or 1)
  constexpr int ASH = BM * 64;            // A tile shorts
  constexpr int TSH = ASH + 256 * 64;     // tile shorts (A + B)
  constexpr int NBUF = (BM == 256) ? 2 : 3;
  __shared__ __align__(128) unsigned short lds[NBUF * TSH];

  int bid = blockIdx.x;
  int b = 0, tm, tn;
  if constexpr (SWZ == 0) {               // QKV: 192 = 8 xcd * (4 tm * 6 tn)
    int xcd = bid & 7, s = bid >> 3;
    tm = xcd * 4 + s / 6; tn = s % 6;
  } else if constexpr (SWZ == 1) {        // score: 256 = 8 xcd * 32 (BM=256)
    int xcd = bid & 7, s = bid >> 3;
    b = xcd >> 1; tm = (xcd & 1) * 4 + (s >> 3); tn = s & 7;
  } else {                                // PV: 256 = 8 xcd * 32 (BM=128)
    int xcd = bid & 7, s = bid >> 3;
    b = xcd >> 1; tm = (xcd & 1) * 8 + (s >> 2); tn = s & 3;
  }

  int t = threadIdx.x, w = t >> 6, l = t & 63;
  int wr = w >> 2, wc = w & 3;            // 2 x 4 wave grid
  int g = l >> 4, c = l & 15;

  f32x4 acc[WM / 16][4];
  #pragma unroll
  for (int m = 0; m < WM / 16; ++m)
    #pragma unroll
    for (int n = 0; n < 4; ++n) acc[m][n] = (f32x4){0.f, 0.f, 0.f, 0.f};

  int srow = t >> 3;                      // 0..63 row within 64-row round
  int scb = (t & 7) * 16;                 // 16B chunk byte offset in 128B row

  const unsigned short* aptr = A + (long)b * batchA + (long)(tm * BM) * lda;
  const unsigned short* bptr = B + (long)b * batchB + (long)(tn * 256) * ldb;

  int kb = scb ^ ((srow & 7) << 4);       // inverse-swizzled source chunk

  auto stageA = [&](int buf, int k0, int r) {   // one 64-row round of A
    int row = r * 64 + srow;
    gload16(aptr + (long)row * lda + k0 + (kb >> 1),
            lds + buf * TSH + r * 4096 + t * 8);
  };
  auto stageB = [&](int buf, int k0, int r) {   // one 64-row round of B
    int row = r * 64 + srow;
    gload16(bptr + (long)row * ldb + k0 + (kb >> 1),
            lds + buf * TSH + ASH + r * 4096 + t * 8);
  };

  auto ldA = [&](const char* abase, int mh, int kh, int m) {
    int row = wr * WM + mh * 64 + m * 16 + c;
    int pb = row * 128 + (kh * 32 + g * 8) * 2;
    pb ^= ((pb >> 7) & 7) << 4;
    return *reinterpret_cast<const bf16x8*>(abase + pb);
  };
  auto ldB = [&](const char* bbase, int kh, int n) {
    int row = wc * 64 + n * 16 + c;
    int pb = row * 128 + (kh * 32 + g * 8) * 2;
    pb ^= ((pb >> 7) & 7) << 4;
    return *reinterpret_cast<const bf16x8*>(bbase + pb);
  };

  if constexpr (BM == 256) {
    // ---- 2-buffer, 4-phase pipeline ----
    // prologue: stage tile 0 fully, drain, barrier
    stageB(0, 0, 0); stageB(0, 0, 1); stageB(0, 0, 2); stageB(0, 0, 3);
    stageA(0, 0, 0); stageA(0, 0, 2); stageA(0, 0, 1); stageA(0, 0, 3);
    asm volatile("s_waitcnt vmcnt(0)" ::: "memory");
    __builtin_amdgcn_s_barrier();

    for (int kt = 0; kt < NT; ++kt) {
      int cur = kt & 1, nb = cur ^ 1;
      const char* abase = (const char*)(lds + cur * TSH);
      const char* bbase = (const char*)(lds + cur * TSH + ASH);
      bool more = (kt + 1) < NT;
      int k1 = (kt + 1) * 64;
      bf16x8 bfr[4];
      #pragma unroll
      for (int p = 0; p < 4; ++p) {
        const int kh = p >> 1, mh = p & 1;
        bf16x8 af[4];
        #pragma unroll
        for (int m = 0; m < 4; ++m) af[m] = ldA(abase, mh, kh, m);
        if (mh == 0) {
          #pragma unroll
          for (int n = 0; n < 4; ++n) bfr[n] = ldB(bbase, kh, n);
        }
        if (more) {
          if      (p == 0) { stageB(nb, k1, 0); stageB(nb, k1, 1); }
          else if (p == 1) { stageB(nb, k1, 2); stageB(nb, k1, 3); }
          else if (p == 2) { stageA(nb, k1, 0); stageA(nb, k1, 2); }
          else             { stageA(nb, k1, 1); stageA(nb, k1, 3); }
        }
        __builtin_amdgcn_s_barrier();
        asm volatile("s_waitcnt lgkmcnt(0)" ::: "memory");
        __builtin_amdgcn_sched_barrier(0);
        __builtin_amdgcn_s_setprio(1);
        #pragma unroll
        for (int m = 0; m < 4; ++m)
          #pragma unroll
          for (int n = 0; n < 4; ++n)
            acc[mh * 4 + m][n] = MFMA(af[m], bfr[n], acc[mh * 4 + m][n]);
        __builtin_amdgcn_s_setprio(0);
        if (p == 0) {                     // retire this tile's A1,A3
          if (kt == NT - 1) asm volatile("s_waitcnt vmcnt(0)" ::: "memory");
          else              asm volatile("s_waitcnt vmcnt(2)" ::: "memory");
        }
        if (p == 3 && more) {             // retire next tile's B*4 + A0,A2
          asm volatile("s_waitcnt vmcnt(2)" ::: "memory");
        }
        __builtin_amdgcn_s_barrier();
      }
    }
  } else {
    // ---- 3-buffer, 2-phase pipeline (r4-proven waits) ----
    // per tile: 6 loads (B rounds 0..3, A rounds 0..1)
    auto stage6 = [&](int buf, int kt2, int ph) {
      int k0 = kt2 * 64;
      if (ph == 0) { stageB(buf, k0, 0); stageB(buf, k0, 1); stageB(buf, k0, 2); }
      else         { stageB(buf, k0, 3); stageA(buf, k0, 0); stageA(buf, k0, 1); }
    };
    stage6(0, 0, 0); stage6(0, 0, 1);
    stage6(1, 1, 0); stage6(1, 1, 1);
    asm volatile("s_waitcnt vmcnt(6)" ::: "memory");
    __builtin_amdgcn_s_barrier();

    for (int kt = 0; kt < NT; ++kt) {
      int cur = kt % 3, nb = (kt + 2) % 3;
      const char* abase = (const char*)(lds + cur * TSH);
      const char* bbase = (const char*)(lds + cur * TSH + ASH);
      bool more2 = (kt + 2) < NT;
      #pragma unroll
      for (int p = 0; p < 2; ++p) {
        const int kh = p;
        bf16x8 af[4], bfr[4];
        #pragma unroll
        for (int m = 0; m < 4; ++m) af[m] = ldA(abase, 0, kh, m);
        #pragma unroll
        for (int n = 0; n < 4; ++n) bfr[n] = ldB(bbase, kh, n);
        if (more2) stage6(nb, kt + 2, p);
        __builtin_amdgcn_s_barrier();
        asm volatile("s_waitcnt lgkmcnt(0)" ::: "memory");
        __builtin_amdgcn_sched_barrier(0);
        __builtin_amdgcn_s_setprio(1);
        #pragma unroll
        for (int m = 0; m < 4; ++m)
          #pragma unroll
          for (int n = 0; n < 4; ++n)
            acc[m][n] = MFMA(af[m], bfr[n], acc[m][n]);
        __builtin_amdgcn_s_setprio(0);
        if (p == 1) {                     // counted wait: tile kt+1 complete
          if (kt < NT - 2)       asm volatile("s_waitcnt vmcnt(6)" ::: "memory");
          else if (kt == NT - 2) asm volatile("s_waitcnt vmcnt(0)" ::: "memory");
        }
        __builtin_amdgcn_s_barrier();
      }
    }
  }

  // ---- epilogue: C/D layout col = lane&15, row = (lane>>4)*4 + j ----
  // acc row mi -> row offset (mi/4)*64 + (mi%4)*16 (works for both WM)
  int rbase = tm * BM + wr * WM + g * 4;
  int c0 = tn * 256 + wc * 64 + c;

  if constexpr (EXPSUM) {
    __shared__ float lred[4][BM];
    #pragma unroll
    for (int mi = 0; mi < WM / 16; ++mi) {
      int roff = (mi / 4) * 64 + (mi % 4) * 16;
      #pragma unroll
      for (int j = 0; j < 4; ++j) {
        long ob = (long)b * batchC + (long)(rbase + roff + j) * ldc + c0;
        float rs = 0.f;
        #pragma unroll
        for (int n = 0; n < 4; ++n) {
          float pv = __expf(acc[mi][n][j] * SCALE);
          ((unsigned short*)Cout)[ob + n * 16] = f2b(pv);
          rs += pv;
        }
        rs += __shfl_xor(rs, 1); rs += __shfl_xor(rs, 2);
        rs += __shfl_xor(rs, 4); rs += __shfl_xor(rs, 8);
        if (c == 0) lred[wc][wr * WM + roff + g * 4 + j] = rs;
      }
    }
    __syncthreads();
    for (int rr = t; rr < BM; rr += 512) {
      float s = lred[0][rr] + lred[1][rr] + lred[2][rr] + lred[3][rr];
      lpart[((long)b * 2048 + tm * BM + rr) * 8 + tn] = s;
    }
  } else {
    #pragma unroll
    for (int mi = 0; mi < WM / 16; ++mi) {
      int roff = (mi / 4) * 64 + (mi % 4) * 16;
      float lv[4];
      if (RS) {
        #pragma unroll
        for (int j = 0; j < 4; ++j)
          lv[j] = rowscale[(long)b * 2048 + rbase + roff + j];
      }
      #pragma unroll
      for (int n = 0; n < 4; ++n) {
        int col = c0 + n * 16;
        float bv = BIAS ? bias[col] : 0.f;
        long rowb = (long)b * batchC + (long)(rbase + roff) * ldc + col;
        #pragma unroll
        for (int j = 0; j < 4; ++j) {
          float v = acc[mi][n][j] + bv;
          if (RS) v *= lv[j];
          if (BF16OUT) ((unsigned short*)Cout)[rowb + (long)j * ldc] = f2b(v);
          else         ((float*)Cout)[rowb + (long)j * ldc] = v;
        }
      }
    }
  }
}

// ---- 1/rowsum (8 partials per row) -----------------------------------------
__global__ __launch_bounds__(256) void linv_kern(const float* __restrict__ lpart,
                                                 float* __restrict__ linv) {
  int r = blockIdx.x * 256 + threadIdx.x;  // 8192 rows
  float s = 0.f;
  #pragma unroll
  for (int i = 0; i < 8; ++i) s += lpart[(long)r * 8 + i];
  linv[r] = 1.f / s;
}

extern "C" void kernel_launch(void* const* d_in, const int* in_sizes, int n_in,
                              void* d_out, int out_size, void* d_ws, size_t ws_size,
                              hipStream_t stream) {
  (void)in_sizes; (void)n_in; (void)out_size; (void)ws_size;
  const float* x  = (const float*)d_in[0];
  const float* Wq = (const float*)d_in[1];
  const float* bq = (const float*)d_in[2];
  const float* Wk = (const float*)d_in[3];
  const float* bk = (const float*)d_in[4];
  const float* Wv = (const float*)d_in[5];
  const float* bv = (const float*)d_in[6];
  float* out = (float*)d_out;
  char* ws = (char*)d_ws;

  // ws layout (bytes). lpart/linv overlay xb's region: xb is dead after the
  // QKV GEMM, and score/linv run strictly after it (stream-ordered).
  unsigned short* xb   = (unsigned short*)(ws + 0);          // 16,777,216
  float*          lpart= (float*)         (ws + 0);          //    262,144 (overlay)
  float*          linv = (float*)         (ws + 262144);     //     32,768 (overlay)
  unsigned short* wt   = (unsigned short*)(ws + 16777216);   //  3,145,728  [1536][1024]
  float*          bc   = (float*)         (ws + 19922944);   //      6,144
  unsigned short* qkv  = (unsigned short*)(ws + 19929088);   // 25,165,824  [8192][1536]
  unsigned short* vT   = (unsigned short*)(ws + 45094912);   // 16,777,216  [4][1024][2048]
  unsigned short* attn = (unsigned short*)(ws + 61872128);   // 33,554,432  [4][2048][2048]

  convert_x_kern<<<4096, 256, 0, stream>>>(x, xb);
  pack_bias_kern<<<6, 256, 0, stream>>>(bq, bk, bv, bc);
  transpose_w_kern<<<dim3(4, 16), 256, 0, stream>>>(Wq, wt,              256, 1024);
  transpose_w_kern<<<dim3(4, 16), 256, 0, stream>>>(Wk, wt + 256 * 1024, 256, 1024);
  transpose_w_kern<<<dim3(16, 16), 256, 0, stream>>>(Wv, wt + 512 * 1024, 1024, 1024);

  // qkv[8192][1536] = xb[8192][1024] @ wt[1536][1024]^T + bias (BM=256)
  gemm_pi<256, 0, true, true, false, false><<<dim3(192), 512, 0, stream>>>(
      xb, wt, bc, qkv, 16, 1024, 1024, 1536, 0, 0, 0, nullptr, nullptr);

  // vT[b][do][s] = v[b][s][do]
  transpose_v_kern<<<dim3(16, 32, 4), 256, 0, stream>>>(
      qkv + 512, vT, 1536, 2048, (long)2048 * 1536, (long)1024 * 2048);

  // attn[b][q][k] = exp(q.k/16) (unnormalized) + row partial sums (BM=256)
  gemm_pi<256, 1, true, false, false, true><<<dim3(256), 512, 0, stream>>>(
      qkv, qkv + 256, nullptr, attn, 4, 1536, 1536, 2048,
      (long)2048 * 1536, (long)2048 * 1536, (long)2048 * 2048, nullptr, lpart);
  linv_kern<<<32, 256, 0, stream>>>(lpart, linv);

  // out[b][s][do] = (attn[b][s][:] @ vT[b][do][:]^T) * linv[b][s] (BM=128)
  gemm_pi<128, 2, false, false, true, false><<<dim3(256), 512, 0, stream>>>(
      attn, vT, nullptr, out, 32, 2048, 2048, 1024,
      (long)2048 * 2048, (long)1024 * 2048, (long)2048 * 1024, linv, nullptr);
}

// Round 8
// 122.973 us; speedup vs baseline: 1.0753x; 1.0056x over previous
//
#include <hip/hip_runtime.h>
#include <hip/hip_bf16.h>

typedef __attribute__((ext_vector_type(8))) short short8;
typedef __attribute__((ext_vector_type(8))) __bf16 bf16x8;
typedef __attribute__((ext_vector_type(4))) float f32x4;

#define MFMA(a, b, c) __builtin_amdgcn_mfma_f32_16x16x32_bf16((a), (b), (c), 0, 0, 0)
#define SCALE 0.0625f

static __device__ __forceinline__ void gload16(const void* g, void* l) {
  __builtin_amdgcn_global_load_lds(
      (const __attribute__((address_space(1))) void*)g,
      (__attribute__((address_space(3))) void*)l, 16, 0, 0);
}

static __device__ __forceinline__ unsigned short f2b(float f) {
  union { __hip_bfloat16 h; unsigned short u; } cv;
  cv.h = __float2bfloat16(f);
  return cv.u;
}

// ---- x (f32) -> bf16, 8 elems/thread ---------------------------------------
__global__ __launch_bounds__(256) void convert_x_kern(const float* __restrict__ x,
                                                      unsigned short* __restrict__ xb) {
  long i = ((long)blockIdx.x * 256 + threadIdx.x) * 8;
  float4 a = *reinterpret_cast<const float4*>(x + i);
  float4 b = *reinterpret_cast<const float4*>(x + i + 4);
  short8 o;
  o[0] = (short)f2b(a.x); o[1] = (short)f2b(a.y); o[2] = (short)f2b(a.z); o[3] = (short)f2b(a.w);
  o[4] = (short)f2b(b.x); o[5] = (short)f2b(b.y); o[6] = (short)f2b(b.z); o[7] = (short)f2b(b.w);
  *reinterpret_cast<short8*>(xb + i) = o;
}

// ---- pack biases into one [1536] f32 buffer --------------------------------
__global__ void pack_bias_kern(const float* __restrict__ bq, const float* __restrict__ bk,
                               const float* __restrict__ bv, float* __restrict__ bc) {
  int i = blockIdx.x * 256 + threadIdx.x;
  float v = (i < 256) ? bq[i] : (i < 512) ? bk[i - 256] : bv[i - 512];
  bc[i] = v;
}

// ---- transpose f32 [R][C] -> bf16 [C][R], 64x64 tiles ----------------------
__global__ __launch_bounds__(256) void transpose_w_kern(const float* __restrict__ src,
                                                        unsigned short* __restrict__ dst,
                                                        int ldsrc, int lddst) {
  __shared__ __align__(16) unsigned short tile[64][72];
  int r0 = blockIdx.y * 64, c0 = blockIdx.x * 64;
  int t = threadIdx.x;
  #pragma unroll
  for (int it = 0; it < 4; ++it) {
    int idx = it * 1024 + t * 4;
    int row = idx >> 6, col = idx & 63;
    float4 v = *reinterpret_cast<const float4*>(src + (long)(r0 + row) * ldsrc + c0 + col);
    tile[row][col + 0] = f2b(v.x); tile[row][col + 1] = f2b(v.y);
    tile[row][col + 2] = f2b(v.z); tile[row][col + 3] = f2b(v.w);
  }
  __syncthreads();
  #pragma unroll
  for (int it = 0; it < 4; ++it) {
    int idx = it * 1024 + t * 4;
    int orow = idx >> 6, ocol = idx & 63;
    ushort4 o;
    o.x = tile[ocol + 0][orow]; o.y = tile[ocol + 1][orow];
    o.z = tile[ocol + 2][orow]; o.w = tile[ocol + 3][orow];
    *reinterpret_cast<ushort4*>(dst + (long)(c0 + orow) * lddst + r0 + ocol) = o;
  }
}

// ---- transpose bf16 [R][C] -> [C][R], batched (for V) ----------------------
__global__ __launch_bounds__(256) void transpose_v_kern(const unsigned short* __restrict__ src0,
                                                        unsigned short* __restrict__ dst0,
                                                        int ldsrc, int lddst,
                                                        long sbatch, long dbatch) {
  const unsigned short* src = src0 + (long)blockIdx.z * sbatch;
  unsigned short* dst = dst0 + (long)blockIdx.z * dbatch;
  __shared__ __align__(16) unsigned short tile[64][72];
  int r0 = blockIdx.y * 64, c0 = blockIdx.x * 64;
  int t = threadIdx.x;
  #pragma unroll
  for (int it = 0; it < 2; ++it) {
    int idx = it * 2048 + t * 8;
    int row = idx >> 6, col = idx & 63;
    short8 v = *reinterpret_cast<const short8*>(src + (long)(r0 + row) * ldsrc + c0 + col);
    *reinterpret_cast<short8*>(&tile[row][col]) = v;
  }
  __syncthreads();
  #pragma unroll
  for (int it = 0; it < 2; ++it) {
    int idx = it * 2048 + t * 8;
    int orow = idx >> 6, ocol = idx & 63;
    short8 o;
    #pragma unroll
    for (int i = 0; i < 8; ++i) o[i] = (short)tile[ocol + i][orow];
    *reinterpret_cast<short8*>(dst + (long)(c0 + orow) * lddst + r0 + ocol) = o;
  }
}

// ============================================================================
// gemm_pi (unchanged, used for QKV + score): BM=256 4-phase, 2-buffer.
// ============================================================================
template <int BM, int SWZ, bool BF16OUT, bool BIAS, bool RS, bool EXPSUM>
__global__ __launch_bounds__(512, 2) void gemm_pi(
    const unsigned short* __restrict__ A, const unsigned short* __restrict__ B,
    const float* __restrict__ bias, void* __restrict__ Cout,
    int NT, int lda, int ldb, int ldc,
    long batchA, long batchB, long batchC,
    const float* __restrict__ rowscale,
    float* __restrict__ lpart) {
  constexpr int WM = BM / 2;
  constexpr int ASH = BM * 64;
  constexpr int TSH = ASH + 256 * 64;
  __shared__ __align__(128) unsigned short lds[2 * TSH];

  int bid = blockIdx.x;
  int b = 0, tm, tn;
  if constexpr (SWZ == 0) {               // QKV: 192 = 8 xcd * (4 tm * 6 tn)
    int xcd = bid & 7, s = bid >> 3;
    tm = xcd * 4 + s / 6; tn = s % 6;
  } else {                                // score: 256 = 8 xcd * 32 (BM=256)
    int xcd = bid & 7, s = bid >> 3;
    b = xcd >> 1; tm = (xcd & 1) * 4 + (s >> 3); tn = s & 7;
  }

  int t = threadIdx.x, w = t >> 6, l = t & 63;
  int wr = w >> 2, wc = w & 3;
  int g = l >> 4, c = l & 15;

  f32x4 acc[WM / 16][4];
  #pragma unroll
  for (int m = 0; m < WM / 16; ++m)
    #pragma unroll
    for (int n = 0; n < 4; ++n) acc[m][n] = (f32x4){0.f, 0.f, 0.f, 0.f};

  int srow = t >> 3;
  int scb = (t & 7) * 16;
  const unsigned short* aptr = A + (long)b * batchA + (long)(tm * BM) * lda;
  const unsigned short* bptr = B + (long)b * batchB + (long)(tn * 256) * ldb;
  int kb = scb ^ ((srow & 7) << 4);

  auto stageA = [&](int buf, int k0, int r) {
    int row = r * 64 + srow;
    gload16(aptr + (long)row * lda + k0 + (kb >> 1),
            lds + buf * TSH + r * 4096 + t * 8);
  };
  auto stageB = [&](int buf, int k0, int r) {
    int row = r * 64 + srow;
    gload16(bptr + (long)row * ldb + k0 + (kb >> 1),
            lds + buf * TSH + ASH + r * 4096 + t * 8);
  };
  auto ldA = [&](const char* abase, int mh, int kh, int m) {
    int row = wr * WM + mh * 64 + m * 16 + c;
    int pb = row * 128 + (kh * 32 + g * 8) * 2;
    pb ^= ((pb >> 7) & 7) << 4;
    return *reinterpret_cast<const bf16x8*>(abase + pb);
  };
  auto ldB = [&](const char* bbase, int kh, int n) {
    int row = wc * 64 + n * 16 + c;
    int pb = row * 128 + (kh * 32 + g * 8) * 2;
    pb ^= ((pb >> 7) & 7) << 4;
    return *reinterpret_cast<const bf16x8*>(bbase + pb);
  };

  stageB(0, 0, 0); stageB(0, 0, 1); stageB(0, 0, 2); stageB(0, 0, 3);
  stageA(0, 0, 0); stageA(0, 0, 2); stageA(0, 0, 1); stageA(0, 0, 3);
  asm volatile("s_waitcnt vmcnt(0)" ::: "memory");
  __builtin_amdgcn_s_barrier();

  for (int kt = 0; kt < NT; ++kt) {
    int cur = kt & 1, nb = cur ^ 1;
    const char* abase = (const char*)(lds + cur * TSH);
    const char* bbase = (const char*)(lds + cur * TSH + ASH);
    bool more = (kt + 1) < NT;
    int k1 = (kt + 1) * 64;
    bf16x8 bfr[4];
    #pragma unroll
    for (int p = 0; p < 4; ++p) {
      const int kh = p >> 1, mh = p & 1;
      bf16x8 af[4];
      #pragma unroll
      for (int m = 0; m < 4; ++m) af[m] = ldA(abase, mh, kh, m);
      if (mh == 0) {
        #pragma unroll
        for (int n = 0; n < 4; ++n) bfr[n] = ldB(bbase, kh, n);
      }
      if (more) {
        if      (p == 0) { stageB(nb, k1, 0); stageB(nb, k1, 1); }
        else if (p == 1) { stageB(nb, k1, 2); stageB(nb, k1, 3); }
        else if (p == 2) { stageA(nb, k1, 0); stageA(nb, k1, 2); }
        else             { stageA(nb, k1, 1); stageA(nb, k1, 3); }
      }
      __builtin_amdgcn_s_barrier();
      asm volatile("s_waitcnt lgkmcnt(0)" ::: "memory");
      __builtin_amdgcn_sched_barrier(0);
      __builtin_amdgcn_s_setprio(1);
      #pragma unroll
      for (int m = 0; m < 4; ++m)
        #pragma unroll
        for (int n = 0; n < 4; ++n)
          acc[mh * 4 + m][n] = MFMA(af[m], bfr[n], acc[mh * 4 + m][n]);
      __builtin_amdgcn_s_setprio(0);
      if (p == 0) {
        if (kt == NT - 1) asm volatile("s_waitcnt vmcnt(0)" ::: "memory");
        else              asm volatile("s_waitcnt vmcnt(2)" ::: "memory");
      }
      if (p == 3 && more) {
        asm volatile("s_waitcnt vmcnt(2)" ::: "memory");
      }
      __builtin_amdgcn_s_barrier();
    }
  }

  int rbase = tm * BM + wr * WM + g * 4;
  int c0 = tn * 256 + wc * 64 + c;

  if constexpr (EXPSUM) {
    __shared__ float lred[4][BM];
    #pragma unroll
    for (int mi = 0; mi < WM / 16; ++mi) {
      int roff = (mi / 4) * 64 + (mi % 4) * 16;
      #pragma unroll
      for (int j = 0; j < 4; ++j) {
        long ob = (long)b * batchC + (long)(rbase + roff + j) * ldc + c0;
        float rs = 0.f;
        #pragma unroll
        for (int n = 0; n < 4; ++n) {
          float pv = __expf(acc[mi][n][j] * SCALE);
          ((unsigned short*)Cout)[ob + n * 16] = f2b(pv);
          rs += pv;
        }
        rs += __shfl_xor(rs, 1); rs += __shfl_xor(rs, 2);
        rs += __shfl_xor(rs, 4); rs += __shfl_xor(rs, 8);
        if (c == 0) lred[wc][wr * WM + roff + g * 4 + j] = rs;
      }
    }
    __syncthreads();
    for (int rr = t; rr < BM; rr += 512) {
      float s = lred[0][rr] + lred[1][rr] + lred[2][rr] + lred[3][rr];
      lpart[((long)b * 2048 + tm * BM + rr) * 8 + tn] = s;
    }
  } else {
    #pragma unroll
    for (int mi = 0; mi < WM / 16; ++mi) {
      int roff = (mi / 4) * 64 + (mi % 4) * 16;
      float lv[4];
      if (RS) {
        #pragma unroll
        for (int j = 0; j < 4; ++j)
          lv[j] = rowscale[(long)b * 2048 + rbase + roff + j];
      }
      #pragma unroll
      for (int n = 0; n < 4; ++n) {
        int col = c0 + n * 16;
        float bv = BIAS ? bias[col] : 0.f;
        long rowb = (long)b * batchC + (long)(rbase + roff) * ldc + col;
        #pragma unroll
        for (int j = 0; j < 4; ++j) {
          float v = acc[mi][n][j] + bv;
          if (RS) v *= lv[j];
          if (BF16OUT) ((unsigned short*)Cout)[rowb + (long)j * ldc] = f2b(v);
          else         ((float*)Cout)[rowb + (long)j * ldc] = v;
        }
      }
    }
  }
}

// ============================================================================
// gemm_pp (PV): ping-pong role-staggered GEMM. BM=128, BN=256, BK=64.
// 8 waves: G0 = wr0 (rows 0-63), G1 = wr1 (rows 64-127), offset by ONE
// barrier so G1's read phase overlaps G0's MFMA phase and vice versa ->
// LDS pipe and matrix pipes concurrently busy (LDS floor ~1900 cyc/tile).
// Per half-step (kh of tile kt): {read 4A+4B frags | kh1: stage(t+2) +
// G1 vmcnt -> bar -> lgkm(0)+sched_barrier -> setprio(1) 16 MFMA setprio(0)
// -> kh1: G0 vmcnt -> bar}. G1: +1 leading barrier; G0: +1 trailing
// (equal counts). 3-buffer LDS (144KB). vmcnt(6) retires tile t+1's 6
// loads before the barrier that opens ANY wave's first read of t+1 (G1
// waits in read phase, G0 after MFMA -> both precede that barrier).
// Overwrite-safety: last reads of buf (t-1)%3 are lgkm-retired >= 1
// barrier before the earliest stage(t+2) issue into it.
// ============================================================================
__global__ __launch_bounds__(512, 2) void gemm_pp(
    const unsigned short* __restrict__ A, const unsigned short* __restrict__ B,
    float* __restrict__ Cout,
    int NT, int lda, int ldb, int ldc,
    long batchA, long batchB, long batchC,
    const float* __restrict__ rowscale) {
  constexpr int ASH = 128 * 64;           // 8192 shorts (16KB)
  constexpr int TSH = ASH + 256 * 64;     // 24576 shorts (48KB)
  __shared__ __align__(128) unsigned short lds[3 * TSH];

  // XCD map: 256 = 8 xcd * 32; batch -> XCD pair (vT panels L2-resident)
  int bid = blockIdx.x;
  int xcd = bid & 7, s = bid >> 3;
  int b = xcd >> 1;
  int tm = (xcd & 1) * 8 + (s >> 2), tn = s & 3;

  int t = threadIdx.x, w = t >> 6, l = t & 63;
  int wr = w >> 2, wc = w & 3;            // wr = ping-pong group
  int g = l >> 4, c = l & 15;

  f32x4 acc[4][4];
  #pragma unroll
  for (int m = 0; m < 4; ++m)
    #pragma unroll
    for (int n = 0; n < 4; ++n) acc[m][n] = (f32x4){0.f, 0.f, 0.f, 0.f};

  int srow = t >> 3;
  int scb = (t & 7) * 16;
  int kb = scb ^ ((srow & 7) << 4);
  const unsigned short* aptr = A + (long)b * batchA + (long)(tm * 128) * lda;
  const unsigned short* bptr = B + (long)b * batchB + (long)(tn * 256) * ldb;

  auto stage6 = [&](int buf, int kt2) {   // 6 loads: B rounds 0-3, A rounds 0-1
    int k0 = kt2 * 64;
    #pragma unroll
    for (int r = 0; r < 4; ++r) {
      int row = r * 64 + srow;
      gload16(bptr + (long)row * ldb + k0 + (kb >> 1),
              lds + buf * TSH + ASH + r * 4096 + t * 8);
    }
    #pragma unroll
    for (int r = 0; r < 2; ++r) {
      int row = r * 64 + srow;
      gload16(aptr + (long)row * lda + k0 + (kb >> 1),
              lds + buf * TSH + r * 4096 + t * 8);
    }
  };

  // prologue: stage tiles 0,1; wait tile 0; G1 takes +1 barrier offset
  stage6(0, 0); stage6(1, 1);
  asm volatile("s_waitcnt vmcnt(6)" ::: "memory");
  __builtin_amdgcn_s_barrier();
  if (wr == 1) __builtin_amdgcn_s_barrier();

  for (int hs = 0; hs < 2 * NT; ++hs) {
    int kt = hs >> 1, kh = hs & 1;
    const char* abase = (const char*)(lds + (kt % 3) * TSH);
    const char* bbase = abase + ASH * 2;

    bf16x8 af[4], bfr[4];
    #pragma unroll
    for (int m = 0; m < 4; ++m) {
      int row = wr * 64 + m * 16 + c;
      int pb = row * 128 + (kh * 32 + g * 8) * 2;
      pb ^= ((pb >> 7) & 7) << 4;
      af[m] = *reinterpret_cast<const bf16x8*>(abase + pb);
    }
    #pragma unroll
    for (int n = 0; n < 4; ++n) {
      int row = wc * 64 + n * 16 + c;
      int pb = row * 128 + (kh * 32 + g * 8) * 2;
      pb ^= ((pb >> 7) & 7) << 4;
      bfr[n] = *reinterpret_cast<const bf16x8*>(bbase + pb);
    }

    if (kh == 1) {
      if (kt + 2 < NT) stage6((kt + 2) % 3, kt + 2);
      if (wr == 1) {                      // G1 waits in its read phase
        if (kt < NT - 2)       asm volatile("s_waitcnt vmcnt(6)" ::: "memory");
        else if (kt == NT - 2) asm volatile("s_waitcnt vmcnt(0)" ::: "memory");
      }
    }
    __builtin_amdgcn_s_barrier();
    asm volatile("s_waitcnt lgkmcnt(0)" ::: "memory");
    __builtin_amdgcn_sched_barrier(0);
    __builtin_amdgcn_s_setprio(1);
    #pragma unroll
    for (int m = 0; m < 4; ++m)
      #pragma unroll
      for (int n = 0; n < 4; ++n)
        acc[m][n] = MFMA(af[m], bfr[n], acc[m][n]);
    __builtin_amdgcn_s_setprio(0);
    if (kh == 1 && wr == 0) {             // G0 waits after its MFMA phase
      if (kt < NT - 2)       asm volatile("s_waitcnt vmcnt(6)" ::: "memory");
      else if (kt == NT - 2) asm volatile("s_waitcnt vmcnt(0)" ::: "memory");
    }
    __builtin_amdgcn_s_barrier();
  }
  if (wr == 0) __builtin_amdgcn_s_barrier();   // match G1's offset

  // epilogue: f32 out with rowscale
  int rbase = tm * 128 + wr * 64 + g * 4;
  int c0 = tn * 256 + wc * 64 + c;
  #pragma unroll
  for (int mi = 0; mi < 4; ++mi) {
    int roff = mi * 16;
    float lv[4];
    #pragma unroll
    for (int j = 0; j < 4; ++j)
      lv[j] = rowscale[(long)b * 2048 + rbase + roff + j];
    #pragma unroll
    for (int n = 0; n < 4; ++n) {
      int col = c0 + n * 16;
      long rowb = (long)b * batchC + (long)(rbase + roff) * ldc + col;
      #pragma unroll
      for (int j = 0; j < 4; ++j)
        Cout[rowb + (long)j * ldc] = acc[mi][n][j] * lv[j];
    }
  }
}

// ---- 1/rowsum (8 partials per row) -----------------------------------------
__global__ __launch_bounds__(256) void linv_kern(const float* __restrict__ lpart,
                                                 float* __restrict__ linv) {
  int r = blockIdx.x * 256 + threadIdx.x;  // 8192 rows
  float s = 0.f;
  #pragma unroll
  for (int i = 0; i < 8; ++i) s += lpart[(long)r * 8 + i];
  linv[r] = 1.f / s;
}

extern "C" void kernel_launch(void* const* d_in, const int* in_sizes, int n_in,
                              void* d_out, int out_size, void* d_ws, size_t ws_size,
                              hipStream_t stream) {
  (void)in_sizes; (void)n_in; (void)out_size; (void)ws_size;
  const float* x  = (const float*)d_in[0];
  const float* Wq = (const float*)d_in[1];
  const float* bq = (const float*)d_in[2];
  const float* Wk = (const float*)d_in[3];
  const float* bk = (const float*)d_in[4];
  const float* Wv = (const float*)d_in[5];
  const float* bv = (const float*)d_in[6];
  float* out = (float*)d_out;
  char* ws = (char*)d_ws;

  unsigned short* xb   = (unsigned short*)(ws + 0);          // 16,777,216
  float*          lpart= (float*)         (ws + 0);          //    262,144 (overlay)
  float*          linv = (float*)         (ws + 262144);     //     32,768 (overlay)
  unsigned short* wt   = (unsigned short*)(ws + 16777216);   //  3,145,728  [1536][1024]
  float*          bc   = (float*)         (ws + 19922944);   //      6,144
  unsigned short* qkv  = (unsigned short*)(ws + 19929088);   // 25,165,824  [8192][1536]
  unsigned short* vT   = (unsigned short*)(ws + 45094912);   // 16,777,216  [4][1024][2048]
  unsigned short* attn = (unsigned short*)(ws + 61872128);   // 33,554,432  [4][2048][2048]

  convert_x_kern<<<4096, 256, 0, stream>>>(x, xb);
  pack_bias_kern<<<6, 256, 0, stream>>>(bq, bk, bv, bc);
  transpose_w_kern<<<dim3(4, 16), 256, 0, stream>>>(Wq, wt,              256, 1024);
  transpose_w_kern<<<dim3(4, 16), 256, 0, stream>>>(Wk, wt + 256 * 1024, 256, 1024);
  transpose_w_kern<<<dim3(16, 16), 256, 0, stream>>>(Wv, wt + 512 * 1024, 1024, 1024);

  // qkv[8192][1536] = xb[8192][1024] @ wt[1536][1024]^T + bias (BM=256)
  gemm_pi<256, 0, true, true, false, false><<<dim3(192), 512, 0, stream>>>(
      xb, wt, bc, qkv, 16, 1024, 1024, 1536, 0, 0, 0, nullptr, nullptr);

  // vT[b][do][s] = v[b][s][do]
  transpose_v_kern<<<dim3(16, 32, 4), 256, 0, stream>>>(
      qkv + 512, vT, 1536, 2048, (long)2048 * 1536, (long)1024 * 2048);

  // attn[b][q][k] = exp(q.k/16) (unnormalized) + row partial sums (BM=256)
  gemm_pi<256, 1, true, false, false, true><<<dim3(256), 512, 0, stream>>>(
      qkv, qkv + 256, nullptr, attn, 4, 1536, 1536, 2048,
      (long)2048 * 1536, (long)2048 * 1536, (long)2048 * 2048, nullptr, lpart);
  linv_kern<<<32, 256, 0, stream>>>(lpart, linv);

  // out[b][s][do] = (attn[b][s][:] @ vT[b][do][:]^T) * linv[b][s] (ping-pong)
  gemm_pp<<<dim3(256), 512, 0, stream>>>(
      attn, vT, out, 32, 2048, 2048, 1024,
      (long)2048 * 2048, (long)1024 * 2048, (long)2048 * 1024, linv);
}